// Round 3
// baseline (239.117 us; speedup 1.0000x reference)
//
#include <hip/hip_runtime.h>
#include <hip/hip_bf16.h>
#include <stdint.h>

#define DI __device__ __forceinline__

typedef __bf16 bf16x8 __attribute__((ext_vector_type(8)));
typedef __bf16 bf16x4 __attribute__((ext_vector_type(4)));
typedef float f32x4 __attribute__((ext_vector_type(4)));
typedef uint16_t u16x8 __attribute__((ext_vector_type(8)));

// ---------- helpers ----------
DI uint16_t f2bf(float f) {
    union { float f; uint32_t u; } v; v.f = f;
    return (uint16_t)((v.u + 0x7fffu + ((v.u >> 16) & 1u)) >> 16);
}

DI void gload_lds16(const void* g, void* l) {
    __builtin_amdgcn_global_load_lds(
        (const __attribute__((address_space(1))) uint32_t*)g,
        (__attribute__((address_space(3))) uint32_t*)l, 16, 0, 0);
}

// stage a 64x64 bf16 tile (row pitch `pitch` elems) into LDS, linear dest,
// inverse-XOR-swizzled source so reads use byte ^= (row&7)<<4.
DI void stage64_swz(const uint16_t* gbase, int pitch, uint16_t* lds, int tid) {
#pragma unroll
    for (int s = 0; s < 2; ++s) {
        int off  = s * 4096 + tid * 16;     // byte offset in LDS
        int row  = off >> 7;                // 128 B per row
        int slot = (off >> 4) & 7;          // 16 B slot within row
        const uint16_t* gp = gbase + (size_t)row * pitch + ((slot ^ (row & 7)) << 3);
        gload_lds16(gp, (char*)lds + off);
    }
}

// swizzled fragment read: row-major [64][64] bf16 tile, returns 8 bf16 at
// (row, elem ch*32 + g*8 .. +7)
DI bf16x8 ldsfrag(const uint16_t* lds, int row, int ch, int g) {
    int bc = (ch * 64 + g * 16) ^ ((row & 7) << 4);
    return *(const bf16x8*)((const char*)lds + row * 128 + bc);
}

// ---------- elementwise cast f32 -> bf16 (also zeroes the work counter) ----------
__global__ __launch_bounds__(256) void k_cast_bf16(const float* __restrict__ in,
                                                   uint16_t* __restrict__ out, int n8,
                                                   int* __restrict__ counter) {
    int i = blockIdx.x * 256 + threadIdx.x;
    if (i == 0) *counter = 0;
    if (i >= n8) return;
    const float4* p = (const float4*)in + (size_t)i * 2;
    float4 a = p[0], b = p[1];
    u16x8 o;
    o[0] = f2bf(a.x); o[1] = f2bf(a.y); o[2] = f2bf(a.z); o[3] = f2bf(a.w);
    o[4] = f2bf(b.x); o[5] = f2bf(b.y); o[6] = f2bf(b.z); o[7] = f2bf(b.w);
    *(u16x8*)(out + (size_t)i * 8) = o;
}

// ---------- transpose + cast: in f32 [R][Cc] -> out bf16 [Cc][R] ----------
__global__ __launch_bounds__(256) void k_transpose_cast(const float* __restrict__ in,
                                                        uint16_t* __restrict__ out,
                                                        int R, int Cc) {
    __shared__ uint16_t tl[64][66];
    int tid = threadIdx.x;
    int c0 = blockIdx.x * 64, r0 = blockIdx.y * 64;
    int rl = tid >> 2, cch = tid & 3;
#pragma unroll
    for (int j = 0; j < 4; ++j) {
        float4 v = *(const float4*)(in + (size_t)(r0 + rl) * Cc + c0 + cch * 16 + j * 4);
        int cb = cch * 16 + j * 4;
        tl[cb + 0][rl] = f2bf(v.x);
        tl[cb + 1][rl] = f2bf(v.y);
        tl[cb + 2][rl] = f2bf(v.z);
        tl[cb + 3][rl] = f2bf(v.w);
    }
    __syncthreads();
    int cl = tid >> 2, rch = tid & 3;
    u16x8 o0, o1;
#pragma unroll
    for (int e = 0; e < 8; ++e) { o0[e] = tl[cl][rch * 16 + e]; o1[e] = tl[cl][rch * 16 + 8 + e]; }
    uint16_t* op = out + (size_t)(c0 + cl) * R + r0 + rch * 16;
    *(u16x8*)op = o0;
    *(u16x8*)(op + 8) = o1;
}

// ---------- V [bh][2048][64] bf16 -> VT [bh][64][2048] bf16 ----------
__global__ __launch_bounds__(256) void k_transpose_v(const uint16_t* __restrict__ V,
                                                     uint16_t* __restrict__ VT) {
    __shared__ uint16_t tl[64][66];
    int tid = threadIdx.x;
    int bh = blockIdx.y;
    int t0 = blockIdx.x * 64;
    const uint16_t* Vp = V + (size_t)bh * 2048 * 64;
    uint16_t* Tp = VT + (size_t)bh * 64 * 2048;
    int trow = tid >> 2, dch = tid & 3;
#pragma unroll
    for (int s = 0; s < 2; ++s) {
        u16x8 v = *(const u16x8*)(Vp + (size_t)(t0 + trow) * 64 + dch * 16 + s * 8);
#pragma unroll
        for (int e = 0; e < 8; ++e) tl[trow][dch * 16 + s * 8 + e] = v[e];
    }
    __syncthreads();
    int drow = tid >> 2, tch = tid & 3;
    u16x8 o0, o1;
#pragma unroll
    for (int e = 0; e < 8; ++e) { o0[e] = tl[tch * 16 + e][drow]; o1[e] = tl[tch * 16 + 8 + e][drow]; }
    uint16_t* op = Tp + (size_t)drow * 2048 + t0 + tch * 16;
    *(u16x8*)op = o0;
    *(u16x8*)(op + 8) = o1;
}

// ---------- bf16 MFMA GEMM: C[m,n] = A[m,:]·B[n,:] + bias[n] ----------
template <int BM, int BN, int MODE>
__global__ __launch_bounds__(256) void k_gemm(const uint16_t* __restrict__ A,
                                              const uint16_t* __restrict__ Bm,
                                              const float* __restrict__ bias,
                                              float* __restrict__ Cout,
                                              uint16_t* __restrict__ q_ws,
                                              uint16_t* __restrict__ k_ws,
                                              uint16_t* __restrict__ v_ws,
                                              int Ndim, int Kdim) {
    __shared__ uint16_t Al[BM * 64];
    __shared__ uint16_t Bl[BN * 64];
    constexpr int WM = BM / 2, WN = BN / 2, MI = WM / 16, NJ = WN / 16;
    constexpr int AS = BM * 128 / 4096, BS = BN * 128 / 4096;
    int tid = threadIdx.x;
    int wave = tid >> 6, lane = tid & 63, g = lane >> 4, cc = lane & 15;
    int bm = blockIdx.y * BM, bn = blockIdx.x * BN;
    int wr = (wave >> 1) * WM, wc = (wave & 1) * WN;
    f32x4 acc[MI][NJ] = {};

    for (int kt = 0; kt < Kdim; kt += 64) {
        __syncthreads();
#pragma unroll
        for (int s = 0; s < AS; ++s) {
            int off = s * 4096 + tid * 16;
            int row = off >> 7, slot = (off >> 4) & 7;
            gload_lds16(A + (size_t)(bm + row) * Kdim + kt + slot * 8, (char*)Al + off);
        }
#pragma unroll
        for (int s = 0; s < BS; ++s) {
            int off = s * 4096 + tid * 16;
            int row = off >> 7, slot = (off >> 4) & 7;
            gload_lds16(Bm + (size_t)(bn + row) * Kdim + kt + slot * 8, (char*)Bl + off);
        }
        __syncthreads();
        bf16x8 af[MI][2], bfr[NJ][2];
#pragma unroll
        for (int mi = 0; mi < MI; ++mi)
#pragma unroll
            for (int ch = 0; ch < 2; ++ch)
                af[mi][ch] = *(const bf16x8*)((const char*)Al + (wr + mi * 16 + cc) * 128 + ch * 64 + g * 16);
#pragma unroll
        for (int nj = 0; nj < NJ; ++nj)
#pragma unroll
            for (int ch = 0; ch < 2; ++ch)
                bfr[nj][ch] = *(const bf16x8*)((const char*)Bl + (wc + nj * 16 + cc) * 128 + ch * 64 + g * 16);
#pragma unroll
        for (int mi = 0; mi < MI; ++mi)
#pragma unroll
            for (int nj = 0; nj < NJ; ++nj) {
                acc[mi][nj] = __builtin_amdgcn_mfma_f32_16x16x32_bf16(af[mi][0], bfr[nj][0], acc[mi][nj], 0, 0, 0);
                acc[mi][nj] = __builtin_amdgcn_mfma_f32_16x16x32_bf16(af[mi][1], bfr[nj][1], acc[mi][nj], 0, 0, 0);
            }
    }

#pragma unroll
    for (int mi = 0; mi < MI; ++mi)
#pragma unroll
        for (int nj = 0; nj < NJ; ++nj) {
            int n = bn + wc + nj * 16 + cc;
            float bv = bias[n];
            if (MODE == 0) {
                int which = (n >= 1536) ? 2 : (n >= 768 ? 1 : 0);
                int cn = n - which * 768;
                int h = cn >> 6, dd = cn & 63;
                uint16_t* dst = which == 0 ? q_ws : (which == 1 ? k_ws : v_ws);
                float scale = which == 0 ? 0.125f : 1.0f;
#pragma unroll
                for (int r = 0; r < 4; ++r) {
                    int m = bm + wr + mi * 16 + 4 * g + r;
                    int b = m >> 11, t = m & 2047;
                    float val = (acc[mi][nj][r] + bv) * scale;
                    dst[(((size_t)(b * 12 + h)) * 2048 + t) * 64 + dd] = f2bf(val);
                }
            } else {
#pragma unroll
                for (int r = 0; r < 4; ++r) {
                    int m = bm + wr + mi * 16 + 4 * g + r;
                    Cout[(size_t)m * Ndim + n] = acc[mi][nj][r] + bv;
                }
            }
        }
}

// ---------- pass A: row-sums of exp(S) (causal), pipelined K staging ----------
// grid (32 qt, 24 bh), 4 waves. l[bh][q] = sum_{k<=q} exp(S[q][k])
__global__ __launch_bounds__(256) void k_lsum(const uint16_t* __restrict__ Q,
                                              const uint16_t* __restrict__ K,
                                              float* __restrict__ lsum) {
    __shared__ uint16_t Kl[2][64 * 64];
    int tid = threadIdx.x;
    int wave = tid >> 6, lane = tid & 63, g = lane >> 4, cc = lane & 15;
    int qt = blockIdx.x, bh = blockIdx.y, qb = qt * 64, nt = qt + 1;
    const uint16_t* Qp = Q + (size_t)bh * 2048 * 64;
    const uint16_t* Kp = K + (size_t)bh * 2048 * 64;
    const uint16_t* qrp = Qp + (size_t)(qb + 16 * wave + cc) * 64 + g * 8;
    bf16x8 qa0 = *(const bf16x8*)qrp;
    bf16x8 qa1 = *(const bf16x8*)(qrp + 32);
    int myq = qb + 16 * wave + cc;
    float lpart = 0.f;

    stage64_swz(Kp, 64, Kl[0], tid);
    asm volatile("s_waitcnt vmcnt(0)" ::: "memory");
    __builtin_amdgcn_s_barrier();
    int cur = 0;
    for (int ks = 0; ks < nt; ++ks) {
        if (ks + 1 < nt) stage64_swz(Kp + (size_t)(ks + 1) * 4096, 64, Kl[cur ^ 1], tid);
        __builtin_amdgcn_sched_barrier(0);
#pragma unroll
        for (int t = 0; t < 4; ++t) {
            bf16x8 k0 = ldsfrag(Kl[cur], t * 16 + cc, 0, g);
            bf16x8 k1 = ldsfrag(Kl[cur], t * 16 + cc, 1, g);
            f32x4 z = {0.f, 0.f, 0.f, 0.f};
            z = __builtin_amdgcn_mfma_f32_16x16x32_bf16(k0, qa0, z, 0, 0, 0);
            z = __builtin_amdgcn_mfma_f32_16x16x32_bf16(k1, qa1, z, 0, 0, 0);
#pragma unroll
            for (int r = 0; r < 4; ++r) {
                int kabs = ks * 64 + t * 16 + 4 * g + r;
                lpart += (kabs <= myq) ? __expf(z[r]) : 0.f;
            }
        }
        asm volatile("s_waitcnt vmcnt(0)" ::: "memory");
        __builtin_amdgcn_s_barrier();
        cur ^= 1;
    }
    lpart += __shfl_xor(lpart, 16, 64);
    lpart += __shfl_xor(lpart, 32, 64);
    if (lane < 16) lsum[(size_t)bh * 2048 + qb + 16 * wave + lane] = lpart;
}

// ---------- pass B: single heavy pass — attn stores + PV + O ----------
// Dynamic units (bh, qt) descending; pipelined K+V dbuf staging; raw barriers.
__global__ __launch_bounds__(256) void k_attn_store(const uint16_t* __restrict__ Q,
                                                    const uint16_t* __restrict__ K,
                                                    const uint16_t* __restrict__ VT,
                                                    const float* __restrict__ lsum,
                                                    float* __restrict__ attn,
                                                    uint16_t* __restrict__ O,
                                                    int* __restrict__ counter) {
    __shared__ uint16_t Kl[2][64 * 64];
    __shared__ uint16_t Vl[2][64 * 64];
    __shared__ uint16_t Pl[64 * 64];
    __shared__ int s_unit;
    int tid = threadIdx.x;
    int wave = tid >> 6, lane = tid & 63, g = lane >> 4, cc = lane & 15;

    for (;;) {
        __syncthreads();
        if (tid == 0) s_unit = atomicAdd(counter, 1);
        __syncthreads();
        int u = s_unit;
        if (u >= 768) break;
        int qt = 31 - (u / 24);
        int bh = u % 24;
        int qb = qt * 64, nt = qt + 1;
        const uint16_t* Qp = Q + (size_t)bh * 2048 * 64;
        const uint16_t* Kp = K + (size_t)bh * 2048 * 64;
        const uint16_t* Vp = VT + (size_t)bh * 64 * 2048;
        float* ap = attn + (size_t)bh * 2048 * 2048 + (size_t)qb * 2048;

        const uint16_t* qrp = Qp + (size_t)(qb + 16 * wave + cc) * 64 + g * 8;
        bf16x8 qa0 = *(const bf16x8*)qrp;
        bf16x8 qa1 = *(const bf16x8*)(qrp + 32);
        int myq = qb + 16 * wave + cc;
        int prow = 16 * wave + cc;
        float rinv = 1.0f / lsum[(size_t)bh * 2048 + qb + prow];
        f32x4 Oa[4] = {};

        stage64_swz(Kp + (size_t)qb * 0, 64, Kl[0], tid);        // ks = 0
        stage64_swz(Vp, 2048, Vl[0], tid);
        asm volatile("s_waitcnt vmcnt(0)" ::: "memory");
        __builtin_amdgcn_s_barrier();
        int cur = 0;
        for (int ks = 0; ks < nt; ++ks) {
            if (ks + 1 < nt) {
                stage64_swz(Kp + (size_t)(ks + 1) * 4096, 64, Kl[cur ^ 1], tid);
                stage64_swz(Vp + (size_t)(ks + 1) * 64, 2048, Vl[cur ^ 1], tid);
            }
            __builtin_amdgcn_sched_barrier(0);
            // QK^T (S^T layout) -> p -> attn store + P to LDS
#pragma unroll
            for (int t = 0; t < 4; ++t) {
                bf16x8 k0 = ldsfrag(Kl[cur], t * 16 + cc, 0, g);
                bf16x8 k1 = ldsfrag(Kl[cur], t * 16 + cc, 1, g);
                f32x4 z = {0.f, 0.f, 0.f, 0.f};
                z = __builtin_amdgcn_mfma_f32_16x16x32_bf16(k0, qa0, z, 0, 0, 0);
                z = __builtin_amdgcn_mfma_f32_16x16x32_bf16(k1, qa1, z, 0, 0, 0);
                f32x4 pv;
                bf16x4 pb;
#pragma unroll
                for (int r = 0; r < 4; ++r) {
                    int kabs = ks * 64 + t * 16 + 4 * g + r;
                    float p = (kabs <= myq) ? __expf(z[r]) * rinv : 0.f;
                    pv[r] = p;
                    pb[r] = (__bf16)p;
                }
                *(f32x4*)(ap + (size_t)prow * 2048 + ks * 64 + t * 16 + 4 * g) = pv;
                *(bf16x4*)((char*)Pl + prow * 128 + ((t * 32 + 8 * g) ^ ((prow & 7) << 4))) = pb;
            }
            // P round-trip fence (in-wave rows; no block barrier needed)
            asm volatile("s_waitcnt lgkmcnt(0)" ::: "memory");
            __builtin_amdgcn_sched_barrier(0);
            bf16x8 pa0 = ldsfrag(Pl, prow, 0, g);
            bf16x8 pa1 = ldsfrag(Pl, prow, 1, g);
#pragma unroll
            for (int n = 0; n < 4; ++n) {
                bf16x8 v0 = ldsfrag(Vl[cur], n * 16 + cc, 0, g);
                bf16x8 v1 = ldsfrag(Vl[cur], n * 16 + cc, 1, g);
                Oa[n] = __builtin_amdgcn_mfma_f32_16x16x32_bf16(pa0, v0, Oa[n], 0, 0, 0);
                Oa[n] = __builtin_amdgcn_mfma_f32_16x16x32_bf16(pa1, v1, Oa[n], 0, 0, 0);
            }
            asm volatile("s_waitcnt vmcnt(0)" ::: "memory");
            __builtin_amdgcn_s_barrier();
            cur ^= 1;
        }

        // zero-fill upper-triangular tiles
        for (int ks = nt; ks < 32; ++ks) {
            float* zp = ap + (size_t)(tid >> 2) * 2048 + ks * 64 + (tid & 3) * 16;
            f32x4 zz = {0.f, 0.f, 0.f, 0.f};
            *(f32x4*)zp = zz;
            *(f32x4*)(zp + 4) = zz;
            *(f32x4*)(zp + 8) = zz;
            *(f32x4*)(zp + 12) = zz;
        }

        // O epilogue (already normalized: P was scaled by rinv)
        int b = bh / 12, h = bh % 12;
#pragma unroll
        for (int n = 0; n < 4; ++n)
#pragma unroll
            for (int r = 0; r < 4; ++r) {
                int mrow = b * 2048 + qb + 16 * wave + 4 * g + r;
                int col = h * 64 + n * 16 + cc;
                O[(size_t)mrow * 768 + col] = f2bf(Oa[n][r]);
            }
    }
}

// ---------- launcher ----------
extern "C" void kernel_launch(void* const* d_in, const int* in_sizes, int n_in,
                              void* d_out, int out_size, void* d_ws, size_t ws_size,
                              hipStream_t stream) {
    (void)in_sizes; (void)n_in; (void)out_size; (void)ws_size;
    const float* x    = (const float*)d_in[0];
    const float* Wqkv = (const float*)d_in[1];
    const float* bqkv = (const float*)d_in[2];
    const float* Wo   = (const float*)d_in[3];
    const float* bo   = (const float*)d_in[4];
    float* out  = (float*)d_out;
    float* attn = out + (size_t)4096 * 768;

    char* ws = (char*)d_ws;
    uint16_t* xbf   = (uint16_t*)(ws);             // 4096x768 bf16 (reused as Ow)
    uint16_t* WqkvT = (uint16_t*)(ws + 6291456);   // 2304x768 bf16
    uint16_t* WoT   = (uint16_t*)(ws + 9830400);   // 768x768 bf16
    uint16_t* Qw    = (uint16_t*)(ws + 11010048);  // [24][2048][64]
    uint16_t* Kw    = (uint16_t*)(ws + 17301504);  // [24][2048][64]
    uint16_t* Vw    = (uint16_t*)(ws + 23592960);  // [24][2048][64]
    uint16_t* VTw   = (uint16_t*)(ws + 29884416);  // [24][64][2048]
    int* counter    = (int*)(ws + 36175872);       // dynamic work counter
    float* l_ws     = (float*)(ws + 36176128);     // [24][2048] f32 row sums
    uint16_t* Ow    = xbf;                         // xbf dead after QKV GEMM

    k_cast_bf16<<<dim3(1536), 256, 0, stream>>>(x, xbf, 393216, counter);
    k_transpose_cast<<<dim3(36, 12), 256, 0, stream>>>(Wqkv, WqkvT, 768, 2304);
    k_transpose_cast<<<dim3(12, 12), 256, 0, stream>>>(Wo, WoT, 768, 768);
    k_gemm<128, 128, 0><<<dim3(18, 32), 256, 0, stream>>>(xbf, WqkvT, bqkv, nullptr,
                                                          Qw, Kw, Vw, 2304, 768);
    k_transpose_v<<<dim3(32, 24), 256, 0, stream>>>(Vw, VTw);
    k_lsum<<<dim3(32, 24), 256, 0, stream>>>(Qw, Kw, l_ws);
    k_attn_store<<<dim3(512), 256, 0, stream>>>(Qw, Kw, VTw, l_ws, attn, Ow, counter);
    k_gemm<64, 128, 1><<<dim3(6, 64), 256, 0, stream>>>(Ow, WoT, bo, out,
                                                        nullptr, nullptr, nullptr, 768, 768);
}

// Round 4
// 205.375 us; speedup vs baseline: 1.1643x; 1.1643x over previous
//
#include <hip/hip_runtime.h>
#include <hip/hip_bf16.h>
#include <stdint.h>

#define DI __device__ __forceinline__

typedef __bf16 bf16x8 __attribute__((ext_vector_type(8)));
typedef __bf16 bf16x4 __attribute__((ext_vector_type(4)));
typedef float f32x4 __attribute__((ext_vector_type(4)));
typedef uint16_t u16x8 __attribute__((ext_vector_type(8)));

// ---------- helpers ----------
DI uint16_t f2bf(float f) {
    union { float f; uint32_t u; } v; v.f = f;
    return (uint16_t)((v.u + 0x7fffu + ((v.u >> 16) & 1u)) >> 16);
}

DI void gload_lds16(const void* g, void* l) {
    __builtin_amdgcn_global_load_lds(
        (const __attribute__((address_space(1))) uint32_t*)g,
        (__attribute__((address_space(3))) uint32_t*)l, 16, 0, 0);
}

// stage a 64x64 bf16 tile (row pitch `pitch` elems) into LDS, linear dest,
// inverse-XOR-swizzled source so reads use byte ^= (row&7)<<4.
DI void stage64_swz(const uint16_t* gbase, int pitch, uint16_t* lds, int tid) {
#pragma unroll
    for (int s = 0; s < 2; ++s) {
        int off  = s * 4096 + tid * 16;     // byte offset in LDS
        int row  = off >> 7;                // 128 B per row
        int slot = (off >> 4) & 7;          // 16 B slot within row
        const uint16_t* gp = gbase + (size_t)row * pitch + ((slot ^ (row & 7)) << 3);
        gload_lds16(gp, (char*)lds + off);
    }
}

// swizzled fragment read: row-major [64][64] bf16 tile, returns 8 bf16 at
// (row, elem ch*32 + g*8 .. +7)
DI bf16x8 ldsfrag(const uint16_t* lds, int row, int ch, int g) {
    int bc = (ch * 64 + g * 16) ^ ((row & 7) << 4);
    return *(const bf16x8*)((const char*)lds + row * 128 + bc);
}

// ---------- elementwise cast f32 -> bf16 (also zeroes the work counter) ----------
__global__ __launch_bounds__(256) void k_cast_bf16(const float* __restrict__ in,
                                                   uint16_t* __restrict__ out, int n8,
                                                   int* __restrict__ counter) {
    int i = blockIdx.x * 256 + threadIdx.x;
    if (i == 0) *counter = 0;
    if (i >= n8) return;
    const float4* p = (const float4*)in + (size_t)i * 2;
    float4 a = p[0], b = p[1];
    u16x8 o;
    o[0] = f2bf(a.x); o[1] = f2bf(a.y); o[2] = f2bf(a.z); o[3] = f2bf(a.w);
    o[4] = f2bf(b.x); o[5] = f2bf(b.y); o[6] = f2bf(b.z); o[7] = f2bf(b.w);
    *(u16x8*)(out + (size_t)i * 8) = o;
}

// ---------- transpose + cast: in f32 [R][Cc] -> out bf16 [Cc][R] ----------
__global__ __launch_bounds__(256) void k_transpose_cast(const float* __restrict__ in,
                                                        uint16_t* __restrict__ out,
                                                        int R, int Cc) {
    __shared__ uint16_t tl[64][66];
    int tid = threadIdx.x;
    int c0 = blockIdx.x * 64, r0 = blockIdx.y * 64;
    int rl = tid >> 2, cch = tid & 3;
#pragma unroll
    for (int j = 0; j < 4; ++j) {
        float4 v = *(const float4*)(in + (size_t)(r0 + rl) * Cc + c0 + cch * 16 + j * 4);
        int cb = cch * 16 + j * 4;
        tl[cb + 0][rl] = f2bf(v.x);
        tl[cb + 1][rl] = f2bf(v.y);
        tl[cb + 2][rl] = f2bf(v.z);
        tl[cb + 3][rl] = f2bf(v.w);
    }
    __syncthreads();
    int cl = tid >> 2, rch = tid & 3;
    u16x8 o0, o1;
#pragma unroll
    for (int e = 0; e < 8; ++e) { o0[e] = tl[cl][rch * 16 + e]; o1[e] = tl[cl][rch * 16 + 8 + e]; }
    uint16_t* op = out + (size_t)(c0 + cl) * R + r0 + rch * 16;
    *(u16x8*)op = o0;
    *(u16x8*)(op + 8) = o1;
}

// ---------- V [bh][2048][64] bf16 -> VT [bh][64][2048] bf16 ----------
__global__ __launch_bounds__(256) void k_transpose_v(const uint16_t* __restrict__ V,
                                                     uint16_t* __restrict__ VT) {
    __shared__ uint16_t tl[64][66];
    int tid = threadIdx.x;
    int bh = blockIdx.y;
    int t0 = blockIdx.x * 64;
    const uint16_t* Vp = V + (size_t)bh * 2048 * 64;
    uint16_t* Tp = VT + (size_t)bh * 64 * 2048;
    int trow = tid >> 2, dch = tid & 3;
#pragma unroll
    for (int s = 0; s < 2; ++s) {
        u16x8 v = *(const u16x8*)(Vp + (size_t)(t0 + trow) * 64 + dch * 16 + s * 8);
#pragma unroll
        for (int e = 0; e < 8; ++e) tl[trow][dch * 16 + s * 8 + e] = v[e];
    }
    __syncthreads();
    int drow = tid >> 2, tch = tid & 3;
    u16x8 o0, o1;
#pragma unroll
    for (int e = 0; e < 8; ++e) { o0[e] = tl[tch * 16 + e][drow]; o1[e] = tl[tch * 16 + 8 + e][drow]; }
    uint16_t* op = Tp + (size_t)drow * 2048 + t0 + tch * 16;
    *(u16x8*)op = o0;
    *(u16x8*)(op + 8) = o1;
}

// ---------- bf16 MFMA GEMM: C[m,n] = A[m,:]·B[n,:] + bias[n] ----------
// XCD-aware bijective block swizzle (grid total divisible by 8).
template <int BM, int BN, int MODE>
__global__ __launch_bounds__(256) void k_gemm(const uint16_t* __restrict__ A,
                                              const uint16_t* __restrict__ Bm,
                                              const float* __restrict__ bias,
                                              float* __restrict__ Cout,
                                              uint16_t* __restrict__ q_ws,
                                              uint16_t* __restrict__ k_ws,
                                              uint16_t* __restrict__ v_ws,
                                              int Ndim, int Kdim) {
    __shared__ uint16_t Al[BM * 64];
    __shared__ uint16_t Bl[BN * 64];
    constexpr int WM = BM / 2, WN = BN / 2, MI = WM / 16, NJ = WN / 16;
    constexpr int AS = BM * 128 / 4096, BS = BN * 128 / 4096;
    int tid = threadIdx.x;
    int wave = tid >> 6, lane = tid & 63, g = lane >> 4, cc = lane & 15;
    int nwgx = gridDim.x;
    int id = blockIdx.y * nwgx + blockIdx.x;
    int chunk = (nwgx * gridDim.y) >> 3;
    id = (id & 7) * chunk + (id >> 3);
    int bm = (id / nwgx) * BM, bn = (id % nwgx) * BN;
    int wr = (wave >> 1) * WM, wc = (wave & 1) * WN;
    f32x4 acc[MI][NJ] = {};

    for (int kt = 0; kt < Kdim; kt += 64) {
        __syncthreads();
#pragma unroll
        for (int s = 0; s < AS; ++s) {
            int off = s * 4096 + tid * 16;
            int row = off >> 7, slot = (off >> 4) & 7;
            gload_lds16(A + (size_t)(bm + row) * Kdim + kt + slot * 8, (char*)Al + off);
        }
#pragma unroll
        for (int s = 0; s < BS; ++s) {
            int off = s * 4096 + tid * 16;
            int row = off >> 7, slot = (off >> 4) & 7;
            gload_lds16(Bm + (size_t)(bn + row) * Kdim + kt + slot * 8, (char*)Bl + off);
        }
        __syncthreads();
        bf16x8 af[MI][2], bfr[NJ][2];
#pragma unroll
        for (int mi = 0; mi < MI; ++mi)
#pragma unroll
            for (int ch = 0; ch < 2; ++ch)
                af[mi][ch] = *(const bf16x8*)((const char*)Al + (wr + mi * 16 + cc) * 128 + ch * 64 + g * 16);
#pragma unroll
        for (int nj = 0; nj < NJ; ++nj)
#pragma unroll
            for (int ch = 0; ch < 2; ++ch)
                bfr[nj][ch] = *(const bf16x8*)((const char*)Bl + (wc + nj * 16 + cc) * 128 + ch * 64 + g * 16);
#pragma unroll
        for (int mi = 0; mi < MI; ++mi)
#pragma unroll
            for (int nj = 0; nj < NJ; ++nj) {
                acc[mi][nj] = __builtin_amdgcn_mfma_f32_16x16x32_bf16(af[mi][0], bfr[nj][0], acc[mi][nj], 0, 0, 0);
                acc[mi][nj] = __builtin_amdgcn_mfma_f32_16x16x32_bf16(af[mi][1], bfr[nj][1], acc[mi][nj], 0, 0, 0);
            }
    }

#pragma unroll
    for (int mi = 0; mi < MI; ++mi)
#pragma unroll
        for (int nj = 0; nj < NJ; ++nj) {
            int n = bn + wc + nj * 16 + cc;
            float bv = bias[n];
            if (MODE == 0) {
                int which = (n >= 1536) ? 2 : (n >= 768 ? 1 : 0);
                int cn = n - which * 768;
                int h = cn >> 6, dd = cn & 63;
                uint16_t* dst = which == 0 ? q_ws : (which == 1 ? k_ws : v_ws);
                float scale = which == 0 ? 0.125f : 1.0f;
#pragma unroll
                for (int r = 0; r < 4; ++r) {
                    int m = bm + wr + mi * 16 + 4 * g + r;
                    int b = m >> 11, t = m & 2047;
                    float val = (acc[mi][nj][r] + bv) * scale;
                    dst[(((size_t)(b * 12 + h)) * 2048 + t) * 64 + dd] = f2bf(val);
                }
            } else {
#pragma unroll
                for (int r = 0; r < 4; ++r) {
                    int m = bm + wr + mi * 16 + 4 * g + r;
                    Cout[(size_t)m * Ndim + n] = acc[mi][nj][r] + bv;
                }
            }
        }
}

// ---------- fused causal attention, merged two-pass, counted-vmcnt stores ----------
// Dynamic unit = (bh, qt), descending work. Per unit:
//  pass 1: K-only dbuf loop -> row sums l (kept in-register -> rinv)
//  pass 2: K+V dbuf loop -> p = exp(S)*rinv -> f32x4 attn store + bf16 P->LDS
//          -> PV (normalized) ; bottom wait = vmcnt(4): drains stage loads,
//          leaves this visit's 4 attn stores in flight across the barrier.
__global__ __launch_bounds__(256) void k_attn4(const uint16_t* __restrict__ Q,
                                               const uint16_t* __restrict__ K,
                                               const uint16_t* __restrict__ VT,
                                               float* __restrict__ attn,
                                               uint16_t* __restrict__ O,
                                               int* __restrict__ counter) {
    __shared__ uint16_t Kl[2][64 * 64];
    __shared__ uint16_t Vl[2][64 * 64];
    __shared__ uint16_t Pl[64 * 64];
    __shared__ int s_unit;
    int tid = threadIdx.x;
    int wave = tid >> 6, lane = tid & 63, g = lane >> 4, cc = lane & 15;

    for (;;) {
        __syncthreads();
        if (tid == 0) s_unit = atomicAdd(counter, 1);
        __syncthreads();
        int u = s_unit;
        if (u >= 768) break;
        int qt = 31 - (u / 24);
        int bh = u % 24;
        int qb = qt * 64, nt = qt + 1;
        const uint16_t* Qp = Q + (size_t)bh * 2048 * 64;
        const uint16_t* Kp = K + (size_t)bh * 2048 * 64;
        const uint16_t* Vp = VT + (size_t)bh * 64 * 2048;
        float* ap = attn + (size_t)bh * 2048 * 2048 + (size_t)qb * 2048;

        const uint16_t* qrp = Qp + (size_t)(qb + 16 * wave + cc) * 64 + g * 8;
        bf16x8 qa0 = *(const bf16x8*)qrp;
        bf16x8 qa1 = *(const bf16x8*)(qrp + 32);
        int myq = qb + 16 * wave + cc;
        int prow = 16 * wave + cc;

        // ---- pass 1: row sums (K-only, no stores -> vmcnt(0) is just loads) ----
        float lpart = 0.f;
        stage64_swz(Kp, 64, Kl[0], tid);
        asm volatile("s_waitcnt vmcnt(0)" ::: "memory");
        __builtin_amdgcn_s_barrier();
        int cur = 0;
        for (int ks = 0; ks < nt; ++ks) {
            if (ks + 1 < nt) stage64_swz(Kp + (size_t)(ks + 1) * 4096, 64, Kl[cur ^ 1], tid);
            __builtin_amdgcn_sched_barrier(0);
#pragma unroll
            for (int t = 0; t < 4; ++t) {
                bf16x8 k0 = ldsfrag(Kl[cur], t * 16 + cc, 0, g);
                bf16x8 k1 = ldsfrag(Kl[cur], t * 16 + cc, 1, g);
                f32x4 z = {0.f, 0.f, 0.f, 0.f};
                z = __builtin_amdgcn_mfma_f32_16x16x32_bf16(k0, qa0, z, 0, 0, 0);
                z = __builtin_amdgcn_mfma_f32_16x16x32_bf16(k1, qa1, z, 0, 0, 0);
#pragma unroll
                for (int r = 0; r < 4; ++r) {
                    int kabs = ks * 64 + t * 16 + 4 * g + r;
                    lpart += (kabs <= myq) ? __expf(z[r]) : 0.f;
                }
            }
            asm volatile("s_waitcnt vmcnt(0)" ::: "memory");
            __builtin_amdgcn_s_barrier();
            cur ^= 1;
        }
        lpart += __shfl_xor(lpart, 16, 64);
        lpart += __shfl_xor(lpart, 32, 64);
        float rinv = 1.0f / lpart;       // row sum for q-row (qb + 16*wave + cc)

        // ---- pass 2: normalized attn stores + PV ----
        f32x4 Oa[4] = {};
        stage64_swz(Kp, 64, Kl[0], tid);
        stage64_swz(Vp, 2048, Vl[0], tid);
        asm volatile("s_waitcnt vmcnt(0)" ::: "memory");
        __builtin_amdgcn_s_barrier();
        cur = 0;
        for (int ks = 0; ks < nt; ++ks) {
            if (ks + 1 < nt) {
                stage64_swz(Kp + (size_t)(ks + 1) * 4096, 64, Kl[cur ^ 1], tid);
                stage64_swz(Vp + (size_t)(ks + 1) * 64, 2048, Vl[cur ^ 1], tid);
            }
            __builtin_amdgcn_sched_barrier(0);
#pragma unroll
            for (int t = 0; t < 4; ++t) {
                bf16x8 k0 = ldsfrag(Kl[cur], t * 16 + cc, 0, g);
                bf16x8 k1 = ldsfrag(Kl[cur], t * 16 + cc, 1, g);
                f32x4 z = {0.f, 0.f, 0.f, 0.f};
                z = __builtin_amdgcn_mfma_f32_16x16x32_bf16(k0, qa0, z, 0, 0, 0);
                z = __builtin_amdgcn_mfma_f32_16x16x32_bf16(k1, qa1, z, 0, 0, 0);
                f32x4 pv;
                bf16x4 pb;
#pragma unroll
                for (int r = 0; r < 4; ++r) {
                    int kabs = ks * 64 + t * 16 + 4 * g + r;
                    float p = (kabs <= myq) ? __expf(z[r]) * rinv : 0.f;
                    pv[r] = p;
                    pb[r] = (__bf16)p;
                }
                *(f32x4*)(ap + (size_t)prow * 2048 + ks * 64 + t * 16 + 4 * g) = pv;
                *(bf16x4*)((char*)Pl + prow * 128 + ((t * 32 + 8 * g) ^ ((prow & 7) << 4))) = pb;
            }
            // P round-trip fence (wave-private rows; DS is in-order per wave)
            asm volatile("s_waitcnt lgkmcnt(0)" ::: "memory");
            __builtin_amdgcn_sched_barrier(0);
            bf16x8 pa0 = ldsfrag(Pl, prow, 0, g);
            bf16x8 pa1 = ldsfrag(Pl, prow, 1, g);
#pragma unroll
            for (int n = 0; n < 4; ++n) {
                bf16x8 v0 = ldsfrag(Vl[cur], n * 16 + cc, 0, g);
                bf16x8 v1 = ldsfrag(Vl[cur], n * 16 + cc, 1, g);
                Oa[n] = __builtin_amdgcn_mfma_f32_16x16x32_bf16(pa0, v0, Oa[n], 0, 0, 0);
                Oa[n] = __builtin_amdgcn_mfma_f32_16x16x32_bf16(pa1, v1, Oa[n], 0, 0, 0);
            }
            // counted wait: drains this visit's 4 stage loads (issued first),
            // leaves this visit's 4 attn stores outstanding across the barrier
            asm volatile("s_waitcnt vmcnt(4)" ::: "memory");
            __builtin_amdgcn_s_barrier();
            cur ^= 1;
        }

        // zero-fill upper-triangular tiles (stores drain lazily at unit top)
        for (int ks = nt; ks < 32; ++ks) {
            float* zp = ap + (size_t)(tid >> 2) * 2048 + ks * 64 + (tid & 3) * 16;
            f32x4 zz = {0.f, 0.f, 0.f, 0.f};
            *(f32x4*)zp = zz;
            *(f32x4*)(zp + 4) = zz;
            *(f32x4*)(zp + 8) = zz;
            *(f32x4*)(zp + 12) = zz;
        }

        // O epilogue (P was pre-normalized -> Oa already normalized)
        int b = bh / 12, h = bh % 12;
#pragma unroll
        for (int n = 0; n < 4; ++n)
#pragma unroll
            for (int r = 0; r < 4; ++r) {
                int mrow = b * 2048 + qb + 16 * wave + 4 * g + r;
                int col = h * 64 + n * 16 + cc;
                O[(size_t)mrow * 768 + col] = f2bf(Oa[n][r]);
            }
    }
}

// ---------- launcher ----------
extern "C" void kernel_launch(void* const* d_in, const int* in_sizes, int n_in,
                              void* d_out, int out_size, void* d_ws, size_t ws_size,
                              hipStream_t stream) {
    (void)in_sizes; (void)n_in; (void)out_size; (void)ws_size;
    const float* x    = (const float*)d_in[0];
    const float* Wqkv = (const float*)d_in[1];
    const float* bqkv = (const float*)d_in[2];
    const float* Wo   = (const float*)d_in[3];
    const float* bo   = (const float*)d_in[4];
    float* out  = (float*)d_out;
    float* attn = out + (size_t)4096 * 768;

    char* ws = (char*)d_ws;
    uint16_t* xbf   = (uint16_t*)(ws);             // 4096x768 bf16 (reused as Ow)
    uint16_t* WqkvT = (uint16_t*)(ws + 6291456);   // 2304x768 bf16
    uint16_t* WoT   = (uint16_t*)(ws + 9830400);   // 768x768 bf16
    uint16_t* Qw    = (uint16_t*)(ws + 11010048);  // [24][2048][64]
    uint16_t* Kw    = (uint16_t*)(ws + 17301504);  // [24][2048][64]
    uint16_t* Vw    = (uint16_t*)(ws + 23592960);  // [24][2048][64]
    uint16_t* VTw   = (uint16_t*)(ws + 29884416);  // [24][64][2048]
    int* counter    = (int*)(ws + 36175872);       // dynamic work counter
    uint16_t* Ow    = xbf;                         // xbf dead after QKV GEMM

    k_cast_bf16<<<dim3(1536), 256, 0, stream>>>(x, xbf, 393216, counter);
    k_transpose_cast<<<dim3(36, 12), 256, 0, stream>>>(Wqkv, WqkvT, 768, 2304);
    k_transpose_cast<<<dim3(12, 12), 256, 0, stream>>>(Wo, WoT, 768, 768);
    k_gemm<128, 128, 0><<<dim3(18, 32), 256, 0, stream>>>(xbf, WqkvT, bqkv, nullptr,
                                                          Qw, Kw, Vw, 2304, 768);
    k_transpose_v<<<dim3(32, 24), 256, 0, stream>>>(Vw, VTw);
    k_attn4<<<dim3(1024), 256, 0, stream>>>(Qw, Kw, VTw, attn, Ow, counter);
    k_gemm<64, 128, 1><<<dim3(6, 64), 256, 0, stream>>>(Ow, WoT, bo, out,
                                                        nullptr, nullptr, nullptr, 768, 768);
}

// Round 5
// 188.732 us; speedup vs baseline: 1.2670x; 1.0882x over previous
//
#include <hip/hip_runtime.h>
#include <hip/hip_bf16.h>
#include <stdint.h>

#define DI __device__ __forceinline__

typedef __bf16 bf16x8 __attribute__((ext_vector_type(8)));
typedef __bf16 bf16x4 __attribute__((ext_vector_type(4)));
typedef float f32x4 __attribute__((ext_vector_type(4)));
typedef uint16_t u16x8 __attribute__((ext_vector_type(8)));
typedef uint16_t u16x4 __attribute__((ext_vector_type(4)));

// ---------- helpers ----------
DI uint16_t f2bf(float f) {
    union { float f; uint32_t u; } v; v.f = f;
    return (uint16_t)((v.u + 0x7fffu + ((v.u >> 16) & 1u)) >> 16);
}

DI void gload_lds16(const void* g, void* l) {
    __builtin_amdgcn_global_load_lds(
        (const __attribute__((address_space(1))) uint32_t*)g,
        (__attribute__((address_space(3))) uint32_t*)l, 16, 0, 0);
}

// stage a 64x64 bf16 tile (row pitch `pitch` elems) into LDS, linear dest,
// inverse-XOR-swizzled source so reads use byte ^= (row&7)<<4.
DI void stage64_swz(const uint16_t* gbase, int pitch, uint16_t* lds, int tid) {
#pragma unroll
    for (int s = 0; s < 2; ++s) {
        int off  = s * 4096 + tid * 16;     // byte offset in LDS
        int row  = off >> 7;                // 128 B per row
        int slot = (off >> 4) & 7;          // 16 B slot within row
        const uint16_t* gp = gbase + (size_t)row * pitch + ((slot ^ (row & 7)) << 3);
        gload_lds16(gp, (char*)lds + off);
    }
}

// swizzled fragment read: row-major [64][64] bf16 tile, returns 8 bf16 at
// (row, elem ch*32 + g*8 .. +7)
DI bf16x8 ldsfrag(const uint16_t* lds, int row, int ch, int g) {
    int bc = (ch * 64 + g * 16) ^ ((row & 7) << 4);
    return *(const bf16x8*)((const char*)lds + row * 128 + bc);
}

// ---------- elementwise cast f32 -> bf16 (also zeroes the 8 work counters) ----------
__global__ __launch_bounds__(256) void k_cast_bf16(const float* __restrict__ in,
                                                   uint16_t* __restrict__ out, int n8,
                                                   int* __restrict__ counters) {
    int i = blockIdx.x * 256 + threadIdx.x;
    if (i < 8) counters[i] = 0;
    if (i >= n8) return;
    const float4* p = (const float4*)in + (size_t)i * 2;
    float4 a = p[0], b = p[1];
    u16x8 o;
    o[0] = f2bf(a.x); o[1] = f2bf(a.y); o[2] = f2bf(a.z); o[3] = f2bf(a.w);
    o[4] = f2bf(b.x); o[5] = f2bf(b.y); o[6] = f2bf(b.z); o[7] = f2bf(b.w);
    *(u16x8*)(out + (size_t)i * 8) = o;
}

// ---------- transpose + cast: in f32 [R][Cc] -> out bf16 [Cc][R] ----------
__global__ __launch_bounds__(256) void k_transpose_cast(const float* __restrict__ in,
                                                        uint16_t* __restrict__ out,
                                                        int R, int Cc) {
    __shared__ uint16_t tl[64][66];
    int tid = threadIdx.x;
    int c0 = blockIdx.x * 64, r0 = blockIdx.y * 64;
    int rl = tid >> 2, cch = tid & 3;
#pragma unroll
    for (int j = 0; j < 4; ++j) {
        float4 v = *(const float4*)(in + (size_t)(r0 + rl) * Cc + c0 + cch * 16 + j * 4);
        int cb = cch * 16 + j * 4;
        tl[cb + 0][rl] = f2bf(v.x);
        tl[cb + 1][rl] = f2bf(v.y);
        tl[cb + 2][rl] = f2bf(v.z);
        tl[cb + 3][rl] = f2bf(v.w);
    }
    __syncthreads();
    int cl = tid >> 2, rch = tid & 3;
    u16x8 o0, o1;
#pragma unroll
    for (int e = 0; e < 8; ++e) { o0[e] = tl[cl][rch * 16 + e]; o1[e] = tl[cl][rch * 16 + 8 + e]; }
    uint16_t* op = out + (size_t)(c0 + cl) * R + r0 + rch * 16;
    *(u16x8*)op = o0;
    *(u16x8*)(op + 8) = o1;
}

// ---------- bf16 MFMA GEMM: C[m,n] = A[m,:]·B[n,:] + bias[n] ----------
// XCD-aware bijective block swizzle (grid total divisible by 8).
// MODE 0: QKV epilogue — Q,K scatter to [B,H,T,d] bf16 (Q scaled 0.125);
//         V written DIRECTLY TRANSPOSED into VT[bh][d][t] via u16x4 stores
//         (acc rows r=0..3 are consecutive t).
// MODE 1: plain f32 out + bias.
template <int BM, int BN, int MODE>
__global__ __launch_bounds__(256) void k_gemm(const uint16_t* __restrict__ A,
                                              const uint16_t* __restrict__ Bm,
                                              const float* __restrict__ bias,
                                              float* __restrict__ Cout,
                                              uint16_t* __restrict__ q_ws,
                                              uint16_t* __restrict__ k_ws,
                                              uint16_t* __restrict__ vt_ws,
                                              int Ndim, int Kdim) {
    __shared__ uint16_t Al[BM * 64];
    __shared__ uint16_t Bl[BN * 64];
    constexpr int WM = BM / 2, WN = BN / 2, MI = WM / 16, NJ = WN / 16;
    constexpr int AS = BM * 128 / 4096, BS = BN * 128 / 4096;
    int tid = threadIdx.x;
    int wave = tid >> 6, lane = tid & 63, g = lane >> 4, cc = lane & 15;
    int nwgx = gridDim.x;
    int id = blockIdx.y * nwgx + blockIdx.x;
    int chunk = (nwgx * gridDim.y) >> 3;
    id = (id & 7) * chunk + (id >> 3);
    int bm = (id / nwgx) * BM, bn = (id % nwgx) * BN;
    int wr = (wave >> 1) * WM, wc = (wave & 1) * WN;
    f32x4 acc[MI][NJ] = {};

    for (int kt = 0; kt < Kdim; kt += 64) {
        __syncthreads();
#pragma unroll
        for (int s = 0; s < AS; ++s) {
            int off = s * 4096 + tid * 16;
            int row = off >> 7, slot = (off >> 4) & 7;
            gload_lds16(A + (size_t)(bm + row) * Kdim + kt + slot * 8, (char*)Al + off);
        }
#pragma unroll
        for (int s = 0; s < BS; ++s) {
            int off = s * 4096 + tid * 16;
            int row = off >> 7, slot = (off >> 4) & 7;
            gload_lds16(Bm + (size_t)(bn + row) * Kdim + kt + slot * 8, (char*)Bl + off);
        }
        __syncthreads();
        bf16x8 af[MI][2], bfr[NJ][2];
#pragma unroll
        for (int mi = 0; mi < MI; ++mi)
#pragma unroll
            for (int ch = 0; ch < 2; ++ch)
                af[mi][ch] = *(const bf16x8*)((const char*)Al + (wr + mi * 16 + cc) * 128 + ch * 64 + g * 16);
#pragma unroll
        for (int nj = 0; nj < NJ; ++nj)
#pragma unroll
            for (int ch = 0; ch < 2; ++ch)
                bfr[nj][ch] = *(const bf16x8*)((const char*)Bl + (wc + nj * 16 + cc) * 128 + ch * 64 + g * 16);
        __builtin_amdgcn_s_setprio(1);
#pragma unroll
        for (int mi = 0; mi < MI; ++mi)
#pragma unroll
            for (int nj = 0; nj < NJ; ++nj) {
                acc[mi][nj] = __builtin_amdgcn_mfma_f32_16x16x32_bf16(af[mi][0], bfr[nj][0], acc[mi][nj], 0, 0, 0);
                acc[mi][nj] = __builtin_amdgcn_mfma_f32_16x16x32_bf16(af[mi][1], bfr[nj][1], acc[mi][nj], 0, 0, 0);
            }
        __builtin_amdgcn_s_setprio(0);
    }

#pragma unroll
    for (int mi = 0; mi < MI; ++mi)
#pragma unroll
        for (int nj = 0; nj < NJ; ++nj) {
            int n = bn + wc + nj * 16 + cc;
            float bv = bias[n];
            if (MODE == 0) {
                int which = (n >= 1536) ? 2 : (n >= 768 ? 1 : 0);
                int cn = n - which * 768;
                int h = cn >> 6, dd = cn & 63;
                int t0 = bm + wr + mi * 16 + 4 * g;     // 4 consecutive rows (same b)
                int b = t0 >> 11, t = t0 & 2047;
                int bh = b * 12 + h;
                if (which == 2) {
                    u16x4 pv;
#pragma unroll
                    for (int r = 0; r < 4; ++r) pv[r] = f2bf(acc[mi][nj][r] + bv);
                    *(u16x4*)(vt_ws + ((size_t)bh * 64 + dd) * 2048 + t) = pv;
                } else {
                    uint16_t* dst = (which == 0) ? q_ws : k_ws;
                    float scale = (which == 0) ? 0.125f : 1.0f;
#pragma unroll
                    for (int r = 0; r < 4; ++r)
                        dst[((size_t)bh * 2048 + t + r) * 64 + dd] = f2bf((acc[mi][nj][r] + bv) * scale);
                }
            } else {
#pragma unroll
                for (int r = 0; r < 4; ++r) {
                    int m = bm + wr + mi * 16 + 4 * g + r;
                    Cout[(size_t)m * Ndim + n] = acc[mi][nj][r] + bv;
                }
            }
        }
}

// ---------- fused causal attention, per-XCD queues, counted-vmcnt stores ----------
// Queue x (= blockIdx.x & 7) owns bh in {3x,3x+1,3x+2}, units ordered qt-descending.
// All of a bh's K/VT/Q (768 KB; 2.3 MB per XCD) stays L2-resident on one XCD.
//  pass 1: K-only dbuf loop -> row sums l (in-register rinv)
//  pass 2: K+V dbuf -> p = exp(S)*rinv -> f32x4 attn store + bf16 P->LDS -> PV;
//          bottom wait = vmcnt(4): drains stage loads, leaves attn stores in flight.
__global__ __launch_bounds__(256) void k_attn5(const uint16_t* __restrict__ Q,
                                               const uint16_t* __restrict__ K,
                                               const uint16_t* __restrict__ VT,
                                               float* __restrict__ attn,
                                               uint16_t* __restrict__ O,
                                               int* __restrict__ counters) {
    __shared__ uint16_t Kl[2][64 * 64];
    __shared__ uint16_t Vl[2][64 * 64];
    __shared__ uint16_t Pl[64 * 64];
    __shared__ int s_unit;
    int tid = threadIdx.x;
    int wave = tid >> 6, lane = tid & 63, g = lane >> 4, cc = lane & 15;
    int qx = blockIdx.x & 7;                 // XCD heuristic (round-robin dispatch)

    for (;;) {
        __syncthreads();
        if (tid == 0) s_unit = atomicAdd(&counters[qx], 1);
        __syncthreads();
        int u = s_unit;
        if (u >= 96) break;
        int qt = 31 - (u / 3);               // heaviest first
        int bh = qx * 3 + (u % 3);
        int qb = qt * 64, nt = qt + 1;
        const uint16_t* Qp = Q + (size_t)bh * 2048 * 64;
        const uint16_t* Kp = K + (size_t)bh * 2048 * 64;
        const uint16_t* Vp = VT + (size_t)bh * 64 * 2048;
        float* ap = attn + (size_t)bh * 2048 * 2048 + (size_t)qb * 2048;

        const uint16_t* qrp = Qp + (size_t)(qb + 16 * wave + cc) * 64 + g * 8;
        bf16x8 qa0 = *(const bf16x8*)qrp;
        bf16x8 qa1 = *(const bf16x8*)(qrp + 32);
        int myq = qb + 16 * wave + cc;
        int prow = 16 * wave + cc;

        // ---- pass 1: row sums (K-only) ----
        float lpart = 0.f;
        stage64_swz(Kp, 64, Kl[0], tid);
        asm volatile("s_waitcnt vmcnt(0)" ::: "memory");
        __builtin_amdgcn_s_barrier();
        int cur = 0;
        for (int ks = 0; ks < nt; ++ks) {
            if (ks + 1 < nt) stage64_swz(Kp + (size_t)(ks + 1) * 4096, 64, Kl[cur ^ 1], tid);
            __builtin_amdgcn_sched_barrier(0);
#pragma unroll
            for (int t = 0; t < 4; ++t) {
                bf16x8 k0 = ldsfrag(Kl[cur], t * 16 + cc, 0, g);
                bf16x8 k1 = ldsfrag(Kl[cur], t * 16 + cc, 1, g);
                f32x4 z = {0.f, 0.f, 0.f, 0.f};
                __builtin_amdgcn_s_setprio(1);
                z = __builtin_amdgcn_mfma_f32_16x16x32_bf16(k0, qa0, z, 0, 0, 0);
                z = __builtin_amdgcn_mfma_f32_16x16x32_bf16(k1, qa1, z, 0, 0, 0);
                __builtin_amdgcn_s_setprio(0);
#pragma unroll
                for (int r = 0; r < 4; ++r) {
                    int kabs = ks * 64 + t * 16 + 4 * g + r;
                    lpart += (kabs <= myq) ? __expf(z[r]) : 0.f;
                }
            }
            asm volatile("s_waitcnt vmcnt(0)" ::: "memory");
            __builtin_amdgcn_s_barrier();
            cur ^= 1;
        }
        lpart += __shfl_xor(lpart, 16, 64);
        lpart += __shfl_xor(lpart, 32, 64);
        float rinv = 1.0f / lpart;

        // ---- pass 2: normalized attn stores + PV ----
        f32x4 Oa[4] = {};
        stage64_swz(Kp, 64, Kl[0], tid);
        stage64_swz(Vp, 2048, Vl[0], tid);
        asm volatile("s_waitcnt vmcnt(0)" ::: "memory");
        __builtin_amdgcn_s_barrier();
        cur = 0;
        for (int ks = 0; ks < nt; ++ks) {
            if (ks + 1 < nt) {
                stage64_swz(Kp + (size_t)(ks + 1) * 4096, 64, Kl[cur ^ 1], tid);
                stage64_swz(Vp + (size_t)(ks + 1) * 64, 2048, Vl[cur ^ 1], tid);
            }
            __builtin_amdgcn_sched_barrier(0);
#pragma unroll
            for (int t = 0; t < 4; ++t) {
                bf16x8 k0 = ldsfrag(Kl[cur], t * 16 + cc, 0, g);
                bf16x8 k1 = ldsfrag(Kl[cur], t * 16 + cc, 1, g);
                f32x4 z = {0.f, 0.f, 0.f, 0.f};
                __builtin_amdgcn_s_setprio(1);
                z = __builtin_amdgcn_mfma_f32_16x16x32_bf16(k0, qa0, z, 0, 0, 0);
                z = __builtin_amdgcn_mfma_f32_16x16x32_bf16(k1, qa1, z, 0, 0, 0);
                __builtin_amdgcn_s_setprio(0);
                f32x4 pv;
                bf16x4 pb;
#pragma unroll
                for (int r = 0; r < 4; ++r) {
                    int kabs = ks * 64 + t * 16 + 4 * g + r;
                    float p = (kabs <= myq) ? __expf(z[r]) * rinv : 0.f;
                    pv[r] = p;
                    pb[r] = (__bf16)p;
                }
                *(f32x4*)(ap + (size_t)prow * 2048 + ks * 64 + t * 16 + 4 * g) = pv;
                *(bf16x4*)((char*)Pl + prow * 128 + ((t * 32 + 8 * g) ^ ((prow & 7) << 4))) = pb;
            }
            // P round-trip fence (wave-private rows; DS in-order per wave)
            asm volatile("s_waitcnt lgkmcnt(0)" ::: "memory");
            __builtin_amdgcn_sched_barrier(0);
            bf16x8 pa0 = ldsfrag(Pl, prow, 0, g);
            bf16x8 pa1 = ldsfrag(Pl, prow, 1, g);
            __builtin_amdgcn_s_setprio(1);
#pragma unroll
            for (int n = 0; n < 4; ++n) {
                bf16x8 v0 = ldsfrag(Vl[cur], n * 16 + cc, 0, g);
                bf16x8 v1 = ldsfrag(Vl[cur], n * 16 + cc, 1, g);
                Oa[n] = __builtin_amdgcn_mfma_f32_16x16x32_bf16(pa0, v0, Oa[n], 0, 0, 0);
                Oa[n] = __builtin_amdgcn_mfma_f32_16x16x32_bf16(pa1, v1, Oa[n], 0, 0, 0);
            }
            __builtin_amdgcn_s_setprio(0);
            // counted wait: drains the 4 stage loads, attn stores stay in flight
            asm volatile("s_waitcnt vmcnt(4)" ::: "memory");
            __builtin_amdgcn_s_barrier();
            cur ^= 1;
        }

        // zero-fill upper-triangular tiles
        for (int ks = nt; ks < 32; ++ks) {
            float* zp = ap + (size_t)(tid >> 2) * 2048 + ks * 64 + (tid & 3) * 16;
            f32x4 zz = {0.f, 0.f, 0.f, 0.f};
            *(f32x4*)zp = zz;
            *(f32x4*)(zp + 4) = zz;
            *(f32x4*)(zp + 8) = zz;
            *(f32x4*)(zp + 12) = zz;
        }

        // O epilogue (P pre-normalized -> Oa already normalized)
        int b = bh / 12, h = bh % 12;
#pragma unroll
        for (int n = 0; n < 4; ++n)
#pragma unroll
            for (int r = 0; r < 4; ++r) {
                int mrow = b * 2048 + qb + 16 * wave + 4 * g + r;
                int col = h * 64 + n * 16 + cc;
                O[(size_t)mrow * 768 + col] = f2bf(Oa[n][r]);
            }
    }
}

// ---------- launcher ----------
extern "C" void kernel_launch(void* const* d_in, const int* in_sizes, int n_in,
                              void* d_out, int out_size, void* d_ws, size_t ws_size,
                              hipStream_t stream) {
    (void)in_sizes; (void)n_in; (void)out_size; (void)ws_size;
    const float* x    = (const float*)d_in[0];
    const float* Wqkv = (const float*)d_in[1];
    const float* bqkv = (const float*)d_in[2];
    const float* Wo   = (const float*)d_in[3];
    const float* bo   = (const float*)d_in[4];
    float* out  = (float*)d_out;
    float* attn = out + (size_t)4096 * 768;

    char* ws = (char*)d_ws;
    uint16_t* xbf   = (uint16_t*)(ws);             // 4096x768 bf16 (reused as Ow)
    uint16_t* WqkvT = (uint16_t*)(ws + 6291456);   // 2304x768 bf16
    uint16_t* WoT   = (uint16_t*)(ws + 9830400);   // 768x768 bf16
    uint16_t* Qw    = (uint16_t*)(ws + 11010048);  // [24][2048][64]
    uint16_t* Kw    = (uint16_t*)(ws + 17301504);  // [24][2048][64]
    uint16_t* VTw   = (uint16_t*)(ws + 29884416);  // [24][64][2048]
    int* counters   = (int*)(ws + 36175872);       // 8 per-XCD work counters
    uint16_t* Ow    = xbf;                         // xbf dead after QKV GEMM

    k_cast_bf16<<<dim3(1536), 256, 0, stream>>>(x, xbf, 393216, counters);
    k_transpose_cast<<<dim3(36, 12), 256, 0, stream>>>(Wqkv, WqkvT, 768, 2304);
    k_transpose_cast<<<dim3(12, 12), 256, 0, stream>>>(Wo, WoT, 768, 768);
    k_gemm<128, 128, 0><<<dim3(18, 32), 256, 0, stream>>>(xbf, WqkvT, bqkv, nullptr,
                                                          Qw, Kw, VTw, 2304, 768);
    k_attn5<<<dim3(1024), 256, 0, stream>>>(Qw, Kw, VTw, attn, Ow, counters);
    k_gemm<64, 128, 1><<<dim3(6, 64), 256, 0, stream>>>(Ow, WoT, bo, out,
                                                        nullptr, nullptr, nullptr, 768, 768);
}